// Round 4
// baseline (16821.739 us; speedup 1.0000x reference)
//
#include <hip/hip_runtime.h>
#include <stdint.h>

#define NCU 256
#define TPB 512
#define IN_DIM 1024
#define HID1   1024
#define HID2   2048
#define T_STEPS 2048

typedef float    f32x4 __attribute__((ext_vector_type(4)));
typedef uint32_t u32x4 __attribute__((ext_vector_type(4)));
typedef uint32_t u32x2 __attribute__((ext_vector_type(2)));

__device__ __forceinline__ float bf_lo(uint32_t u){ return __uint_as_float(u << 16); }
__device__ __forceinline__ float bf_hi(uint32_t u){ return __uint_as_float(u & 0xffff0000u); }
__device__ __forceinline__ uint32_t f2bf(float f){
  uint32_t x = __float_as_uint(f);
  return (x + 0x7fffu + ((x >> 16) & 1u)) >> 16;   // RNE
}
__device__ __forceinline__ uint32_t pack2(float a, float b){
  return f2bf(a) | (f2bf(b) << 16);
}
__device__ __forceinline__ float wave_reduce(float v){
  v += __shfl_xor(v, 32); v += __shfl_xor(v, 16); v += __shfl_xor(v, 8);
  v += __shfl_xor(v, 4);  v += __shfl_xor(v, 2);  v += __shfl_xor(v, 1);
  return v;
}
__device__ __forceinline__ float sigmoidf_(float x){ return 1.0f / (1.0f + expf(-x)); }

// Exchange line: 24 dwords = 12 pairs {payload, tag}. Pairs 0..3 = h1 (fp32),
// pairs 4..11 = h2 (fp32). 4 buffers deep (t&3). RCCL-LL-style: 8B stores are
// visible atomically, so the tag arriving == the payload arriving.
#define LINE_DW 24

__global__ void prep_kernel(uint32_t* __restrict__ combined)
{
  int idx = blockIdx.x * blockDim.x + threadIdx.x;
  const int total = 4 * NCU * LINE_DW;
  for (int i = idx; i < total; i += gridDim.x * blockDim.x)
    __hip_atomic_store(combined + i, 0u, __ATOMIC_RELAXED, __HIP_MEMORY_SCOPE_AGENT);
}

// ---------------------------------------------------------------------------
// persistent 2-layer LSTM scan. 256 blocks (1/CU) x 512 threads.
// Block b owns layer1 units [4b,4b+4) and layer2 units [8b,8b+8).
// Iteration t computes h1[t] (phase A, needs h1[t-1]) and h2[t-2]
// (phase B, needs h1[t-2], h2[t-3]) -> layer-2 chain has a full iteration
// of slack; only h1 publish->phaseA is latency-critical.
// One global exchange (publish 12 tagged pairs / poll+gather) per iteration.
// ---------------------------------------------------------------------------
__global__ __launch_bounds__(TPB, 1) void lstm_persist(
    const float* __restrict__ x,    const float* __restrict__ Wih1,
    const float* __restrict__ Whh1, const float* __restrict__ b1,
    const float* __restrict__ Wih2, const float* __restrict__ Whh2,
    const float* __restrict__ b2,   const float* __restrict__ Wout,
    uint32_t* __restrict__ combined, float* __restrict__ partial_out)
{
  // 128 KiB: 32 rows x 256 u32x4; u4 index u holds elements [4u..4u+3] and
  // [1024+4u..1024+4u+3] of the row -> all per-step LDS reads contiguous.
  __shared__ u32x4 whh2_u4[32 * 256];
  __shared__ f32x4 h1buf[2][HID1 / 4];   // double-buffered h1 (2 x 4 KiB)
  __shared__ f32x4 h2_4[HID2 / 4];       // h2[t-3] (8 KiB)
  __shared__ float gsum1[16], gx1v[16], gsum2[32], b2v[32];

  const int b    = blockIdx.x;
  const int tid  = threadIdx.x;
  const int lane = tid & 63;
  const int wv   = tid >> 6;   // 8 waves

  // ---- init: stage Whh2 slice into LDS (fp32 -> bf16, paired-block layout) --
  for (int i = tid; i < 32 * 256; i += TPB) {
    int lr = i >> 8, u = i & 255;
    int g = lr >> 3, uu2 = lr & 7;
    const f32x4* s4 = (const f32x4*)(Whh2 + (int64_t)(g * HID2 + 8 * b + uu2) * HID2);
    f32x4 lo = s4[u], hi = s4[256 + u];
    u32x4 wv4;
    wv4[0] = pack2(lo[0], lo[1]); wv4[1] = pack2(lo[2], lo[3]);
    wv4[2] = pack2(hi[0], hi[1]); wv4[3] = pack2(hi[2], hi[3]);
    whh2_u4[i] = wv4;
  }

  // ---- Whh1 slice in registers (fp32, 2 rows/wave, 16 elems/lane/row) ----
  float w1r[2][16];
  int rows1[2];
  #pragma unroll
  for (int rr = 0; rr < 2; ++rr) {
    int lr1 = wv * 2 + rr;
    int g = lr1 >> 2, uu = lr1 & 3;
    int row = g * HID1 + 4 * b + uu;
    rows1[rr] = row;
    #pragma unroll
    for (int j = 0; j < 16; ++j)
      w1r[rr][j] = Whh1[(int64_t)row * IN_DIM + lane + 64 * j];
  }

  // ---- Wih2 slice in registers (bf16 packed, paired-block layout) ----
  u32x4 wi_reg[4][2];
  #pragma unroll
  for (int rr = 0; rr < 4; ++rr) {
    int lr = wv * 4 + rr;
    int g = lr >> 3, uu = lr & 7;
    const f32x4* s4 = (const f32x4*)(Wih2 + (int64_t)(g * HID2 + 8 * b + uu) * IN_DIM);
    #pragma unroll
    for (int q = 0; q < 2; ++q) {
      int u = lane + 64 * q;
      f32x4 lo = s4[u], hi = s4[128 + u];
      u32x4 wv4;
      wv4[0] = pack2(lo[0], lo[1]); wv4[1] = pack2(lo[2], lo[3]);
      wv4[2] = pack2(hi[0], hi[1]); wv4[3] = pack2(hi[2], hi[3]);
      wi_reg[rr][q] = wv4;
    }
  }

  // ---- gx1 = Wih1 @ x + b1 (constant over t) ----
  #pragma unroll
  for (int rr = 0; rr < 2; ++rr) {
    int row = rows1[rr];
    float s = 0.f;
    #pragma unroll
    for (int j = 0; j < 16; ++j)
      s += Wih1[(int64_t)row * IN_DIM + lane + 64 * j] * x[lane + 64 * j];
    s = wave_reduce(s);
    if (lane == 0) gx1v[wv * 2 + rr] = s + b1[row];
  }
  if (tid < 32) { int g = tid >> 3, uu = tid & 7; b2v[tid] = b2[g * HID2 + 8 * b + uu]; }
  {
    float* h1a = (float*)h1buf[0];
    float* h1bb = (float*)h1buf[1];
    float* h2a = (float*)h2_4;
    for (int i = tid; i < HID1; i += TPB) { h1a[i] = 0.f; h1bb[i] = 0.f; }
    for (int i = tid; i < HID2; i += TPB) h2a[i] = 0.f;
  }

  const float woutreg = Wout[8 * b + (lane & 7)];
  float c1reg = 0.f, c2reg = 0.f;
  __syncthreads();

  // ---- time loop ----
  for (int t = 0; t < T_STEPS + 2; ++t) {
    if (t < T_STEPS) {
      // Phase A: layer1 recurrent matvec over h1[t-1] (freshest buffer)
      const float* h1A = (const float*)h1buf[(t + 1) & 1];
      #pragma unroll
      for (int rr = 0; rr < 2; ++rr) {
        float s = 0.f;
        #pragma unroll
        for (int j = 0; j < 16; ++j) s += w1r[rr][j] * h1A[lane + 64 * j];
        s = wave_reduce(s);
        if (lane == 0) gsum1[wv * 2 + rr] = s;
      }
    }
    if (t >= 2) {
      // Phase B: layer2 matvec: Wih2(reg bf16)*h1[t-2] + Whh2(LDS bf16)*h2[t-3]
      const f32x4* h1B = h1buf[t & 1];
      #pragma unroll
      for (int rr = 0; rr < 4; ++rr) {
        const int lr = wv * 4 + rr;
        float s = 0.f;
        #pragma unroll
        for (int q = 0; q < 2; ++q) {
          const int u = lane + 64 * q;
          u32x4 w = wi_reg[rr][q];
          f32x4 ha = h1B[u];
          f32x4 hb = h1B[128 + u];
          s += bf_lo(w[0]) * ha[0] + bf_hi(w[0]) * ha[1]
             + bf_lo(w[1]) * ha[2] + bf_hi(w[1]) * ha[3];
          s += bf_lo(w[2]) * hb[0] + bf_hi(w[2]) * hb[1]
             + bf_lo(w[3]) * hb[2] + bf_hi(w[3]) * hb[3];
        }
        #pragma unroll
        for (int q = 0; q < 4; ++q) {
          const int u = lane + 64 * q;
          u32x4 w = whh2_u4[lr * 256 + u];
          f32x4 ha = h2_4[u];
          f32x4 hb = h2_4[256 + u];
          s += bf_lo(w[0]) * ha[0] + bf_hi(w[0]) * ha[1]
             + bf_lo(w[1]) * ha[2] + bf_hi(w[1]) * ha[3];
          s += bf_lo(w[2]) * hb[0] + bf_hi(w[2]) * hb[1]
             + bf_lo(w[3]) * hb[2] + bf_hi(w[3]) * hb[3];
        }
        s = wave_reduce(s);
        if (lane == 0) gsum2[lr] = s;
      }
    }
    __syncthreads();   // gsums ready; all LDS h reads of this iter done

    if (wv == 0) {
      // gates + publish (12 tagged 8B pairs, no fences, no store-ack wait)
      float h1v = 0.f, h2v = 0.f;
      if (t < T_STEPS) {
        const int u1 = lane & 3;
        float gi = sigmoidf_(gsum1[u1]      + gx1v[u1]);
        float gf = sigmoidf_(gsum1[4 + u1]  + gx1v[4 + u1]);
        float gg = tanhf    (gsum1[8 + u1]  + gx1v[8 + u1]);
        float go = sigmoidf_(gsum1[12 + u1] + gx1v[12 + u1]);
        c1reg = gf * c1reg + gi * gg;
        h1v = go * tanhf(c1reg);               // unit (lane&3)
      }
      if (t >= 2) {
        const int u2 = lane & 7;
        float gi = sigmoidf_(gsum2[u2]      + b2v[u2]);
        float gf = sigmoidf_(gsum2[8 + u2]  + b2v[8 + u2]);
        float gg = tanhf    (gsum2[16 + u2] + b2v[16 + u2]);
        float go = sigmoidf_(gsum2[24 + u2] + b2v[24 + u2]);
        c2reg = gf * c2reg + gi * gg;
        h2v = go * tanhf(c2reg);               // unit (lane&7)
        float contrib = (lane < 8) ? h2v * woutreg : 0.f;
        float po = wave_reduce(contrib);
        if (lane == 0) partial_out[(int64_t)(t - 2) * NCU + b] = po;
      }
      // pair k: k<4 -> h1 unit k ; k>=4 -> h2 unit k-4
      int src = (lane >= 4 && lane < 12) ? (lane - 4) : 0;
      float h2s = __shfl(h2v, src);
      float payload = (lane < 4) ? h1v : h2s;
      if (lane < 12) {
        uint32_t* p = combined + ((size_t)(t & 3) * NCU + b) * LINE_DW + 2 * lane;
        u32x2 st;
        st[0] = __float_as_uint(payload);
        st[1] = (uint32_t)(t + 1);
        asm volatile("global_store_dwordx2 %0, %1, off sc0 sc1"
                     :: "v"(p), "v"(st) : "memory");
      }
    }

    // waves 4..7: poll+gather one line each (poll IS the gather)
    if (tid >= NCU) {
      const int j = tid - NCU;
      const uint32_t* line = combined + ((size_t)(t & 3) * NCU + j) * LINE_DW;
      const uint32_t tg = (uint32_t)(t + 1);
      // stage 1: cheap probe on the last pair's tag
      u32x2 q;
      for (;;) {
        asm volatile("global_load_dwordx2 %0, %1, off offset:88 sc0 sc1"
                     : "=&v"(q) : "v"(line));
        asm volatile("s_waitcnt vmcnt(0)" ::: "memory");
        if (q[1] == tg) break;
        __builtin_amdgcn_s_sleep(1);
      }
      // stage 2: full load, verify every tag (stores may land out of order)
      u32x4 p0, p1, p2, p3, p4, p5;
      for (;;) {
        asm volatile("global_load_dwordx4 %0, %1, off sc0 sc1"
                     : "=&v"(p0) : "v"(line));
        asm volatile("global_load_dwordx4 %0, %1, off offset:16 sc0 sc1"
                     : "=&v"(p1) : "v"(line));
        asm volatile("global_load_dwordx4 %0, %1, off offset:32 sc0 sc1"
                     : "=&v"(p2) : "v"(line));
        asm volatile("global_load_dwordx4 %0, %1, off offset:48 sc0 sc1"
                     : "=&v"(p3) : "v"(line));
        asm volatile("global_load_dwordx4 %0, %1, off offset:64 sc0 sc1"
                     : "=&v"(p4) : "v"(line));
        asm volatile("global_load_dwordx4 %0, %1, off offset:80 sc0 sc1"
                     : "=&v"(p5) : "v"(line));
        asm volatile("s_waitcnt vmcnt(0)" ::: "memory");
        bool ok = (p0[1]==tg) & (p0[3]==tg) & (p1[1]==tg) & (p1[3]==tg)
                & (p2[1]==tg) & (p2[3]==tg) & (p3[1]==tg) & (p3[3]==tg)
                & (p4[1]==tg) & (p4[3]==tg) & (p5[1]==tg) & (p5[3]==tg);
        if (ok) break;
        __builtin_amdgcn_s_sleep(1);
      }
      f32x4 h1w;
      h1w[0] = __uint_as_float(p0[0]); h1w[1] = __uint_as_float(p0[2]);
      h1w[2] = __uint_as_float(p1[0]); h1w[3] = __uint_as_float(p1[2]);
      h1buf[t & 1][j] = h1w;             // becomes h1[t]
      f32x4 h2a, h2b;
      h2a[0] = __uint_as_float(p2[0]); h2a[1] = __uint_as_float(p2[2]);
      h2a[2] = __uint_as_float(p3[0]); h2a[3] = __uint_as_float(p3[2]);
      h2b[0] = __uint_as_float(p4[0]); h2b[1] = __uint_as_float(p4[2]);
      h2b[2] = __uint_as_float(p5[0]); h2b[3] = __uint_as_float(p5[2]);
      h2_4[2 * j]     = h2a;             // becomes h2[t-2]
      h2_4[2 * j + 1] = h2b;
    }
    __syncthreads();
  }
}

// ---------------------------------------------------------------------------
// out[t] = sum_b partial_out[t][b] + bout
// ---------------------------------------------------------------------------
__global__ void out_reduce(const float* __restrict__ partial_out,
                           const float* __restrict__ bout,
                           float* __restrict__ out)
{
  int t = blockIdx.x;
  int lane = threadIdx.x;   // 64 threads
  float s = 0.f;
  #pragma unroll
  for (int q = 0; q < 4; ++q) s += partial_out[(int64_t)t * NCU + lane + 64 * q];
  s = wave_reduce(s);
  if (lane == 0) out[t] = s + bout[0];
}

extern "C" void kernel_launch(void* const* d_in, const int* in_sizes, int n_in,
                              void* d_out, int out_size, void* d_ws, size_t ws_size,
                              hipStream_t stream)
{
  const float* x    = (const float*)d_in[0];
  const float* Wih1 = (const float*)d_in[1];
  const float* Whh1 = (const float*)d_in[2];
  const float* b1   = (const float*)d_in[3];
  const float* Wih2 = (const float*)d_in[4];
  const float* Whh2 = (const float*)d_in[5];
  const float* b2   = (const float*)d_in[6];
  const float* Wout = (const float*)d_in[7];
  const float* bout = (const float*)d_in[8];
  float* out = (float*)d_out;

  char* ws = (char*)d_ws;
  size_t off = 0;
  auto take = [&](size_t bytes) -> char* {
    char* p = ws + off;
    off = (off + bytes + 255) & ~(size_t)255;
    return p;
  };
  uint32_t* combined  = (uint32_t*)take((size_t)4 * NCU * LINE_DW * 4);  // 96 KB
  float* partial_out  = (float*)take((size_t)T_STEPS * NCU * 4);         // 2 MB

  if (off > ws_size) return;

  hipLaunchKernelGGL(prep_kernel, dim3(32), dim3(256), 0, stream, combined);

  void* args[] = { &x, &Wih1, &Whh1, &b1, &Wih2, &Whh2, &b2, &Wout,
                   &combined, &partial_out };
  (void)hipLaunchCooperativeKernel((void*)lstm_persist, dim3(NCU), dim3(TPB),
                                   args, 0, stream);

  hipLaunchKernelGGL(out_reduce, dim3(T_STEPS), dim3(64), 0, stream,
                     partial_out, bout, out);
}